// Round 5
// baseline (27687.097 us; speedup 1.0000x reference)
//
#include <hip/hip_runtime.h>
#include <hip/hip_bf16.h>
#include <math.h>

// TitanMini forward: B=1024, S=65 (CLS+64), D=512, H=8, DK=64, DFF=1536 (GEGLU), L=10
// Runtime input-dtype detection (f32 vs bf16) -> all input reads go through ld();
// internal pipeline bf16 (GEMM) + fp32 residual; output emitted in detected dtype.
// 8 batch-chunks of 128; per-(chunk,layer) weight transpose into rotating wbuf. ~111 MB ws.

typedef short short8 __attribute__((ext_vector_type(8)));
typedef float f32x4 __attribute__((ext_vector_type(4)));

#define NLAYER 10
#define DMODEL 512
#define NHEAD 8
#define BATCH 1024
#define SEQ 65
#define NCHUNK 8
#define BCH (BATCH/NCHUNK)      // 128
#define MCH (BCH*SEQ)           // 8320 = 65*128

// wbuf element offsets
#define WB_QKV   0L
#define WB_WO    786432L
#define WB_W1    1048576L
#define WB_W2    2621440L
#define WB_BQKV  3407872L
#define WB_BO    3409408L
#define WB_B1    3409920L
#define WB_B2    3412992L
#define WB_TOTAL 3413504L

__device__ __forceinline__ float bf2f(ushort u){ return __uint_as_float(((unsigned)u)<<16); }
__device__ __forceinline__ ushort f2bf(float f){
  unsigned u = __float_as_uint(f);
  unsigned r = (u + 0x7fffu + ((u>>16)&1u)) >> 16;
  return (ushort)r;
}
__device__ __forceinline__ float gelu_exact(float x){
  return 0.5f*x*(1.0f+erff(x*0.70710678118654752440f));
}
// dt==1: input is bf16; dt==0: input is f32
__device__ __forceinline__ float ld(const void* p, long i, int dt){
  return dt ? bf2f(((const ushort*)p)[i]) : ((const float*)p)[i];
}

// ---------------- input dtype probe: any bf16 NaN/Inf pattern in emb_W => f32 ----------------
__global__ void detect_kernel(const ushort* __restrict__ embW, int* __restrict__ flag){
  __shared__ int cnt;
  if(threadIdx.x==0) cnt=0;
  __syncthreads();
  int c=0;
  for(int i=threadIdx.x;i<8192;i+=256){
    ushort u=embW[i];
    if(((u>>7)&0xFF)==0xFF) c++;       // bf16 exp all-ones -> Inf/NaN pattern
  }
  if(c) atomicAdd(&cnt,c);
  __syncthreads();
  if(threadIdx.x==0) *flag = (cnt>0)?0:1;
}

// ---------------- per-layer weight prep: transpose qkv/wo/w1/w2 + biases -> bf16 wbuf ----------------
__global__ void prep_layer(const void* Wq, const void* Wk, const void* Wv, const void* Wo,
                           const void* W1, const void* W2,
                           const void* bq, const void* bk, const void* bv,
                           const void* bo, const void* b1, const void* b2,
                           ushort* __restrict__ wbuf, int l, const int* __restrict__ dtp)
{
  long idx = (long)blockIdx.x*256 + threadIdx.x;
  if(idx >= WB_TOTAL) return;
  const int dt = *dtp;
  if(idx < WB_WO){                       // qkvT: [n<1536][k<512]
    long r = idx;
    int n = (int)(r>>9), k = (int)(r&511);
    float v;
    if(n<512)       v = ld(Wq,(long)l*262144 + (long)k*512 + n, dt);
    else if(n<1024) v = ld(Wk,(long)l*262144 + (long)k*512 + (n-512), dt);
    else            v = ld(Wv,(long)l*262144 + (long)k*512 + (n-1024), dt);
    wbuf[WB_QKV + (long)n*512 + k] = f2bf(v);
  } else if(idx < WB_W1){                // woT: [n<512][k<512]
    long r = idx - WB_WO;
    int n = (int)(r>>9), k = (int)(r&511);
    wbuf[WB_WO + (long)n*512 + k] = f2bf(ld(Wo,(long)l*262144 + (long)k*512 + n, dt));
  } else if(idx < WB_W2){                // w1T: [n<3072][k<512]
    long r = idx - WB_W1;
    int n = (int)(r>>9), k = (int)(r&511);
    wbuf[WB_W1 + (long)n*512 + k] = f2bf(ld(W1,(long)l*1572864 + (long)k*3072 + n, dt));
  } else if(idx < WB_BQKV){              // w2T: [n<512][k<1536]
    long r = idx - WB_W2;
    int n = (int)(r/1536), k = (int)(r - (long)n*1536);
    wbuf[WB_W2 + r] = f2bf(ld(W2,(long)l*786432 + (long)k*512 + n, dt));
  } else if(idx < WB_BO){                // bqkv
    int n = (int)(idx - WB_BQKV);
    float v;
    if(n<512) v=ld(bq,l*512+n,dt); else if(n<1024) v=ld(bk,l*512+n-512,dt); else v=ld(bv,l*512+n-1024,dt);
    wbuf[idx] = f2bf(v);
  } else if(idx < WB_B1){
    wbuf[idx] = f2bf(ld(bo, l*512 + (int)(idx-WB_BO), dt));
  } else if(idx < WB_B2){
    wbuf[idx] = f2bf(ld(b1, l*3072 + (int)(idx-WB_B1), dt));
  } else {
    wbuf[idx] = f2bf(ld(b2, l*512 + (int)(idx-WB_B2), dt));
  }
}

// ---------------- embedding + positional tables -> t (fp32), chunk-local ----------------
__global__ __launch_bounds__(64) void embed_kernel(
    const void* x, const void* emb_W, const void* emb_b, const void* cls,
    const void* abs_pos, const void* file_tab, const void* rank_tab,
    const void* diag_tab, const void* anti_tab,
    float* __restrict__ t, long xoff, const int* __restrict__ dtp)
{
  const int dt = *dtp;
  long tok = blockIdx.x;
  int lane = threadIdx.x;
  long b = tok/SEQ;
  int s = (int)(tok - b*SEQ);
  float* out = t + tok*DMODEL;
  if(s==0){
    #pragma unroll
    for(int j=0;j<8;j++){ int d=lane*8+j; out[d]=ld(cls,d,dt); }
    return;
  }
  int p = s-1;
  int f = p&7, r = p>>3;
  int dg = r+f, ad = r-f+7;
  float xv[16];
  #pragma unroll
  for(int k=0;k<16;k++) xv[k]=ld(x, xoff + (b*64+p)*16+k, dt);
  #pragma unroll
  for(int j=0;j<8;j++){
    int d = lane*8+j;
    float acc = ld(emb_b,d,dt) + ld(abs_pos,p*512+d,dt) + ld(file_tab,f*512+d,dt)
              + ld(rank_tab,r*512+d,dt) + ld(diag_tab,dg*512+d,dt) + ld(anti_tab,ad*512+d,dt);
    #pragma unroll
    for(int k=0;k<16;k++) acc += xv[k]*ld(emb_W,k*512+d,dt);
    out[d]=acc;
  }
}

// ---------------- LayerNorm: t(fp32) -> h(bf16) ----------------
__global__ __launch_bounds__(64) void ln_kernel(const float* __restrict__ t, ushort* __restrict__ h,
                                                const void* g, const void* b,
                                                long goff, const int* __restrict__ dtp)
{
  const int dt = *dtp;
  long tok = blockIdx.x;
  int lane = threadIdx.x;
  const float* row = t + tok*DMODEL;
  float4 v0 = *reinterpret_cast<const float4*>(row + lane*8);
  float4 v1 = *reinterpret_cast<const float4*>(row + lane*8 + 4);
  float x[8] = {v0.x,v0.y,v0.z,v0.w,v1.x,v1.y,v1.z,v1.w};
  float s=0.f, ss=0.f;
  #pragma unroll
  for(int j=0;j<8;j++){ s+=x[j]; ss+=x[j]*x[j]; }
  #pragma unroll
  for(int off=32;off>=1;off>>=1){ s+=__shfl_down(s,off); ss+=__shfl_down(ss,off); }
  s=__shfl(s,0); ss=__shfl(ss,0);
  float mean = s*(1.0f/512.0f);
  float var  = ss*(1.0f/512.0f) - mean*mean;
  float rs = rsqrtf(fmaxf(var,0.0f) + 1e-5f);
  #pragma unroll
  for(int j=0;j<8;j++){
    int d=lane*8+j;
    h[tok*DMODEL+d] = f2bf((x[j]-mean)*rs*ld(g,goff+d,dt) + ld(b,goff+d,dt));
  }
}

// ---------------- GEMM: C[M][N] = A[M][lda] @ BT[N][K]^T + bias(bf16 wbuf) ----------------
// EPI 0: Cb = acc+bias (bf16) ; EPI 1: Cf += acc+bias (fp32 residual)
template<int EPI>
__global__ __launch_bounds__(256,2) void gemm_bt(
    const ushort* __restrict__ A, long lda,
    const ushort* __restrict__ BT,
    const ushort* __restrict__ bias,
    ushort* __restrict__ Cb, float* __restrict__ Cf,
    long ldc, int K)
{
  __shared__ __align__(16) ushort As[128*32];
  __shared__ __align__(16) ushort Bs[128*32];
  const int tid = threadIdx.x;
  const int w = tid>>6, lane = tid&63, q = lane>>4, lr = lane&15;
  const int wm = (w>>1)*64, wn = (w&1)*64;
  const long mBase = (long)blockIdx.y*128, nBase = (long)blockIdx.x*128;

  f32x4 acc[4][4];
  #pragma unroll
  for(int i=0;i<4;i++)
    #pragma unroll
    for(int j=0;j<4;j++) acc[i][j]=(f32x4)(0.0f);

  const int idx0=tid, idx1=tid+256;
  const int ar0=idx0>>2, ac0=(idx0&3)*8;
  const int ar1=idx1>>2, ac1=(idx1&3)*8;

  for(int k0=0;k0<K;k0+=32){
    uint4 a0 = *reinterpret_cast<const uint4*>(A  + (mBase+ar0)*lda     + k0 + ac0);
    uint4 a1 = *reinterpret_cast<const uint4*>(A  + (mBase+ar1)*lda     + k0 + ac1);
    uint4 b0 = *reinterpret_cast<const uint4*>(BT + (nBase+ar0)*(long)K + k0 + ac0);
    uint4 b1 = *reinterpret_cast<const uint4*>(BT + (nBase+ar1)*(long)K + k0 + ac1);
    __syncthreads();
    reinterpret_cast<uint4*>(As)[idx0]=a0;
    reinterpret_cast<uint4*>(As)[idx1]=a1;
    reinterpret_cast<uint4*>(Bs)[idx0]=b0;
    reinterpret_cast<uint4*>(Bs)[idx1]=b1;
    __syncthreads();
    short8 af[4], bfr[4];
    #pragma unroll
    for(int mt=0;mt<4;mt++) af[mt]=*reinterpret_cast<const short8*>(As + (wm+mt*16+lr)*32 + q*8);
    #pragma unroll
    for(int nt=0;nt<4;nt++) bfr[nt]=*reinterpret_cast<const short8*>(Bs + (wn+nt*16+lr)*32 + q*8);
    #pragma unroll
    for(int mt=0;mt<4;mt++)
      #pragma unroll
      for(int nt=0;nt<4;nt++)
        acc[mt][nt]=__builtin_amdgcn_mfma_f32_16x16x32_bf16(af[mt],bfr[nt],acc[mt][nt],0,0,0);
  }

  #pragma unroll
  for(int nt=0;nt<4;nt++){
    long n = nBase+wn+nt*16+lr;
    float bv = bf2f(bias[n]);
    #pragma unroll
    for(int mt=0;mt<4;mt++){
      #pragma unroll
      for(int r=0;r<4;r++){
        long m = mBase+wm+mt*16+q*4+r;
        float v = acc[mt][nt][r]+bv;
        if constexpr (EPI==0){
          Cb[m*ldc+n]=f2bf(v);
        } else {
          Cf[m*ldc+n]+=v;
        }
      }
    }
  }
}

// ---------------- fused attention per (b,h): scores+bias+softmax+AV ----------------
__global__ __launch_bounds__(256) void attn_kernel(const ushort* __restrict__ qkv,
                                                   const void* rel_bias,
                                                   ushort* __restrict__ ctx, int layer,
                                                   const int* __restrict__ dtp)
{
  const int dt = *dtp;
  int bh = blockIdx.x;
  long b = bh>>3;
  int h = bh&7;
  __shared__ ushort Qs[SEQ*64], Ks[SEQ*64], Vs[SEQ*64];
  __shared__ float Sc[SEQ*SEQ];
  const long tokBase = b*SEQ;
  for(int idx=threadIdx.x; idx<SEQ*64; idx+=256){
    int s=idx>>6, d=idx&63;
    long base=(tokBase+s)*1536 + h*64 + d;
    Qs[idx]=qkv[base];
    Ks[idx]=qkv[base+512];
    Vs[idx]=qkv[base+1024];
  }
  __syncthreads();
  for(int idx=threadIdx.x; idx<SEQ*SEQ; idx+=256){
    int qi=idx/SEQ, ki=idx-qi*SEQ;
    float s=0.f;
    #pragma unroll 8
    for(int d=0;d<64;d++) s += bf2f(Qs[qi*64+d])*bf2f(Ks[ki*64+d]);
    s *= 0.125f;
    if(qi>0 && ki>0){
      int pq=qi-1, pk=ki-1;
      int ridx=(pq>>3)-(pk>>3)+7, fidx=(pq&7)-(pk&7)+7;
      s += ld(rel_bias, ((long)(layer*15+ridx)*15+fidx)*8+h, dt);
    }
    Sc[idx]=s;
  }
  __syncthreads();
  for(int qi=threadIdx.x; qi<SEQ; qi+=256){
    float mx=-1e30f;
    for(int k=0;k<SEQ;k++) mx=fmaxf(mx,Sc[qi*SEQ+k]);
    float sum=0.f;
    for(int k=0;k<SEQ;k++){ float e=expf(Sc[qi*SEQ+k]-mx); Sc[qi*SEQ+k]=e; sum+=e; }
    float inv=1.0f/sum;
    for(int k=0;k<SEQ;k++) Sc[qi*SEQ+k]*=inv;
  }
  __syncthreads();
  for(int idx=threadIdx.x; idx<SEQ*64; idx+=256){
    int qi=idx>>6, d=idx&63;
    float s=0.f;
    for(int k=0;k<SEQ;k++) s += Sc[qi*SEQ+k]*bf2f(Vs[k*64+d]);
    ctx[(tokBase+qi)*512 + h*64 + d] = f2bf(s);
  }
}

// ---------------- GEGLU: p[tok][j] = gelu(p[tok][j]) * p[tok][j+1536], ld=3072 ----------------
__global__ void geglu_kernel(ushort* __restrict__ p, int total){
  int idx = blockIdx.x*256+threadIdx.x;
  if(idx>=total) return;
  int tok = idx/1536;
  int j = idx - tok*1536;
  long base = (long)tok*3072;
  float x1 = bf2f(p[base+j]);
  float x2 = bf2f(p[base+1536+j]);
  p[base+j] = f2bf(gelu_exact(x1)*x2);
}

// ---------------- policy head -> f32 stage ----------------
__global__ __launch_bounds__(128) void policy_kernel(const ushort* __restrict__ h,
                                                     const void* pol_W, const void* pol_b,
                                                     float* __restrict__ stage, long b0,
                                                     const int* __restrict__ dtp)
{
  const int dt = *dtp;
  int bp = blockIdx.x;           // bl*64 + p
  long bl = bp>>6;
  int p = bp&63;
  const ushort* hrow = h + (bl*SEQ + 1 + p)*DMODEL;
  __shared__ float hl[DMODEL];
  for(int d=threadIdx.x; d<DMODEL; d+=128) hl[d]=bf2f(hrow[d]);
  __syncthreads();
  int j = threadIdx.x;
  if(j<72){
    float acc = ld(pol_b,j,dt);
    for(int k=0;k<DMODEL;k++) acc += hl[k]*ld(pol_W,k*72+j,dt);
    stage[(b0+bl)*4608 + (long)p*72 + j] = acc;
  }
}

// ---------------- value head MLP on CLS token -> f32 stage ----------------
__global__ __launch_bounds__(256) void value_kernel(const ushort* __restrict__ h,
                                                    const void* v1_W, const void* v1_b,
                                                    const void* v2_W, const void* v2_b,
                                                    const void* v3_W, const void* v3_b,
                                                    float* __restrict__ stage, long b0,
                                                    const int* __restrict__ dtp)
{
  const int dt = *dtp;
  long bl = blockIdx.x;
  int tid = threadIdx.x;
  __shared__ float vh[512], a1[256], a2[128];
  const ushort* hrow = h + bl*SEQ*DMODEL;   // CLS token
  for(int d=tid; d<512; d+=256) vh[d]=bf2f(hrow[d]);
  __syncthreads();
  {
    float acc = ld(v1_b,tid,dt);
    for(int k=0;k<512;k++) acc += vh[k]*ld(v1_W,k*256+tid,dt);
    a1[tid]=gelu_exact(acc);
  }
  __syncthreads();
  if(tid<128){
    float acc = ld(v2_b,tid,dt);
    for(int k=0;k<256;k++) acc += a1[k]*ld(v2_W,k*128+tid,dt);
    a2[tid]=gelu_exact(acc);
  }
  __syncthreads();
  if(tid==0){
    float acc = ld(v3_b,0,dt);
    for(int k=0;k<128;k++) acc += a2[k]*ld(v3_W,k,dt);
    stage[(long)BATCH*4608 + b0 + bl] = tanhf(acc);
  }
}

// ---------------- emit: stage (f32) -> d_out in detected dtype ----------------
__global__ void emit_kernel(const float* __restrict__ stage, void* out,
                            const int* __restrict__ dtp, int total)
{
  int i = blockIdx.x*256+threadIdx.x;
  if(i>=total) return;
  if(*dtp) ((ushort*)out)[i] = f2bf(stage[i]);
  else     ((float*)out)[i]  = stage[i];
}

extern "C" void kernel_launch(void* const* d_in, const int* in_sizes, int n_in,
                              void* d_out, int out_size, void* d_ws, size_t ws_size,
                              hipStream_t stream)
{
  const void* x        = d_in[0];
  const void* emb_W    = d_in[1];
  const void* emb_b    = d_in[2];
  const void* cls      = d_in[3];
  const void* abs_pos  = d_in[4];
  const void* file_tab = d_in[5];
  const void* rank_tab = d_in[6];
  const void* diag_tab = d_in[7];
  const void* anti_tab = d_in[8];
  const void* rel_bias = d_in[9];
  const void* Wq  = d_in[10];
  const void* bq  = d_in[11];
  const void* Wk  = d_in[12];
  const void* bk  = d_in[13];
  const void* Wv  = d_in[14];
  const void* bv  = d_in[15];
  const void* Wo  = d_in[16];
  const void* bo  = d_in[17];
  const void* ln1_g = d_in[18];
  const void* ln1_b = d_in[19];
  const void* ln2_g = d_in[20];
  const void* ln2_b = d_in[21];
  const void* W1  = d_in[22];
  const void* b1  = d_in[23];
  const void* W2  = d_in[24];
  const void* b2  = d_in[25];
  const void* fln_g = d_in[26];
  const void* fln_b = d_in[27];
  const void* pol_W = d_in[28];
  const void* pol_b = d_in[29];
  const void* v1_W  = d_in[30];
  const void* v1_b  = d_in[31];
  const void* v2_W  = d_in[32];
  const void* v2_b  = d_in[33];
  const void* v3_W  = d_in[34];
  const void* v3_b  = d_in[35];

  char* ws = (char*)d_ws;
  float*  t    = (float*)ws;  ws += (size_t)MCH*DMODEL*4;     // 17.0 MB
  ushort* h    = (ushort*)ws; ws += (size_t)MCH*DMODEL*2;     //  8.5 MB
  ushort* ctx  = (ushort*)ws; ws += (size_t)MCH*DMODEL*2;     //  8.5 MB
  ushort* buf1 = (ushort*)ws; ws += (size_t)MCH*3072*2;       // 51.1 MB (qkv / ffn p)
  ushort* wbuf = (ushort*)ws; ws += (size_t)WB_TOTAL*2;       //  6.8 MB (one layer's weights^T)
  float*  stage= (float*)ws;  ws += (size_t)(BATCH*4608+BATCH)*4; // 18.9 MB
  int*    dtp  = (int*)ws;    ws += 256;
  (void)ws_size; (void)in_sizes; (void)n_in;
  // total ~111 MB

  const int prepBlocks = (int)((WB_TOTAL + 255) / 256);

  detect_kernel<<<1,256,0,stream>>>((const ushort*)emb_W, dtp);

  // --- per-chunk full network ---
  for(int c=0;c<NCHUNK;c++){
    long b0 = (long)c*BCH;
    embed_kernel<<<MCH,64,0,stream>>>(x, emb_W, emb_b, cls, abs_pos,
                                      file_tab, rank_tab, diag_tab, anti_tab,
                                      t, b0*64*16, dtp);
    for(int l=0;l<NLAYER;l++){
      prep_layer<<<prepBlocks,256,0,stream>>>(Wq,Wk,Wv,Wo,W1,W2,bq,bk,bv,bo,b1,b2, wbuf, l, dtp);
      ln_kernel<<<MCH,64,0,stream>>>(t, h, ln1_g, ln1_b, l*512, dtp);
      gemm_bt<0><<<dim3(12,65),256,0,stream>>>(h, 512, wbuf+WB_QKV, wbuf+WB_BQKV, buf1, nullptr, 1536, 512);
      attn_kernel<<<BCH*NHEAD,256,0,stream>>>(buf1, rel_bias, ctx, l, dtp);
      gemm_bt<1><<<dim3(4,65),256,0,stream>>>(ctx, 512, wbuf+WB_WO, wbuf+WB_BO, nullptr, t, 512, 512);
      ln_kernel<<<MCH,64,0,stream>>>(t, h, ln2_g, ln2_b, l*512, dtp);
      gemm_bt<0><<<dim3(24,65),256,0,stream>>>(h, 512, wbuf+WB_W1, wbuf+WB_B1, buf1, nullptr, 3072, 512);
      { int total = MCH*1536; geglu_kernel<<<(total+255)/256,256,0,stream>>>(buf1, total); }
      gemm_bt<1><<<dim3(4,65),256,0,stream>>>(buf1, 3072, wbuf+WB_W2, wbuf+WB_B2, nullptr, t, 512, 1536);
    }
    ln_kernel<<<MCH,64,0,stream>>>(t, h, fln_g, fln_b, 0, dtp);
    policy_kernel<<<BCH*64,128,0,stream>>>(h, pol_W, pol_b, stage, b0, dtp);
    value_kernel<<<BCH,256,0,stream>>>(h, v1_W, v1_b, v2_W, v2_b, v3_W, v3_b, stage, b0, dtp);
  }
  emit_kernel<<<(out_size+255)/256,256,0,stream>>>(stage, d_out, dtp, out_size);
}

// Round 6
// 17859.346 us; speedup vs baseline: 1.5503x; 1.5503x over previous
//
#include <hip/hip_runtime.h>
#include <hip/hip_bf16.h>
#include <math.h>

// TitanMini forward: B=1024, S=65 (CLS+64), D=512, H=8, DK=64, DFF=1536 (GEGLU), L=10
// Inputs/outputs are FLOAT32 (verified round 5). Internal: bf16 GEMM operands via MFMA,
// fp32 residual stream. NCHUNK=4 (BCH=256); weights transposed to bf16 once per call.
// Fused GEGLU in FFN1 epilogue (interleaved W1^T + shfl_xor pairing).
// Workspace 170.5 MB (round-2 demonstrated-writable extent: 170.6 MB).

typedef short short8 __attribute__((ext_vector_type(8)));
typedef float f32x4 __attribute__((ext_vector_type(4)));

#define NLAYER 10
#define DMODEL 512
#define NHEAD 8
#define BATCH 1024
#define SEQ 65
#define NCHUNK 4
#define BCH (BATCH/NCHUNK)      // 256
#define MCH (BCH*SEQ)           // 16640 = 130*128

// wT element offsets (ushort)
#define WT_QKV   0L            // 10*1536*512
#define WT_WO    7864320L      // 10*512*512
#define WT_W1    10485760L     // 10*3072*512 (columns interleaved x1/x2)
#define WT_W2    26214400L     // 10*512*1536
#define WT_BQKV  34078720L     // 10*1536
#define WT_BO    34094080L     // 10*512
#define WT_B1    34099200L     // 10*3072 (interleaved)
#define WT_B2    34129920L     // 10*512
#define WT_TOTAL 34135040L

__device__ __forceinline__ float bf2f(ushort u){ return __uint_as_float(((unsigned)u)<<16); }
__device__ __forceinline__ ushort f2bf(float f){
  unsigned u = __float_as_uint(f);
  unsigned r = (u + 0x7fffu + ((u>>16)&1u)) >> 16;
  return (ushort)r;
}
__device__ __forceinline__ float gelu_exact(float x){
  return 0.5f*x*(1.0f+erff(x*0.70710678118654752440f));
}

// ---------------- one-time weight prep: f32 -> transposed bf16 ----------------
__global__ void prep_qkv(const float* __restrict__ Wq, const float* __restrict__ Wk,
                         const float* __restrict__ Wv, ushort* __restrict__ wT)
{
  long idx = (long)blockIdx.x*256 + threadIdx.x;
  if(idx >= 7864320L) return;
  int l = (int)(idx/786432L);
  long r = idx - (long)l*786432L;
  int n = (int)(r>>9), k = (int)(r&511);
  float v;
  if(n<512)       v = Wq[(long)l*262144 + (long)k*512 + n];
  else if(n<1024) v = Wk[(long)l*262144 + (long)k*512 + (n-512)];
  else            v = Wv[(long)l*262144 + (long)k*512 + (n-1024)];
  wT[WT_QKV + idx] = f2bf(v);
}
__global__ void prep_wo(const float* __restrict__ Wo, ushort* __restrict__ wT)
{
  long idx = (long)blockIdx.x*256 + threadIdx.x;
  if(idx >= 2621440L) return;
  int l = (int)(idx/262144L);
  long r = idx - (long)l*262144L;
  int n = (int)(r>>9), k = (int)(r&511);
  wT[WT_WO + idx] = f2bf(Wo[(long)l*262144 + (long)k*512 + n]);
}
__global__ void prep_w1(const float* __restrict__ W1, ushort* __restrict__ wT)
{
  long idx = (long)blockIdx.x*256 + threadIdx.x;
  if(idx >= 15728640L) return;
  int l = (int)(idx/1572864L);
  long r = idx - (long)l*1572864L;
  int n = (int)(r>>9), k = (int)(r&511);
  int j = n>>1;
  int src = (n&1) ? 1536+j : j;       // even n -> x1 col j, odd n -> x2 col j
  wT[WT_W1 + idx] = f2bf(W1[(long)l*1572864 + (long)k*3072 + src]);
}
__global__ void prep_w2(const float* __restrict__ W2, ushort* __restrict__ wT)
{
  long idx = (long)blockIdx.x*256 + threadIdx.x;
  if(idx >= 7864320L) return;
  int l = (int)(idx/786432L);
  long r = idx - (long)l*786432L;
  int n = (int)(r/1536), k = (int)(r - (long)n*1536);
  wT[WT_W2 + idx] = f2bf(W2[(long)l*786432 + (long)k*512 + n]);
}
__global__ void prep_bias(const float* __restrict__ bq, const float* __restrict__ bk,
                          const float* __restrict__ bv, const float* __restrict__ bo,
                          const float* __restrict__ b1, const float* __restrict__ b2,
                          ushort* __restrict__ wT)
{
  int idx = blockIdx.x*256 + threadIdx.x;
  if(idx >= 56320) return;
  long o = WT_BQKV + idx;
  float v;
  if(o < WT_BO){
    int i = idx;                 // bqkv: l*1536 + n
    int l = i/1536, n = i - l*1536;
    if(n<512) v=bq[l*512+n]; else if(n<1024) v=bk[l*512+n-512]; else v=bv[l*512+n-1024];
  } else if(o < WT_B1){
    int i = (int)(o - WT_BO);
    v = bo[i];
  } else if(o < WT_B2){
    int i = (int)(o - WT_B1);    // b1 interleaved: l*3072 + n
    int l = i/3072, n = i - l*3072;
    int j=n>>1; int src=(n&1)?1536+j:j;
    v = b1[l*3072+src];
  } else {
    int i = (int)(o - WT_B2);
    v = b2[i];
  }
  wT[o] = f2bf(v);
}

// ---------------- embedding + positional tables -> t (fp32), chunk-local ----------------
__global__ __launch_bounds__(64) void embed_kernel(
    const float* __restrict__ x, const float* __restrict__ emb_W,
    const float* __restrict__ emb_b, const float* __restrict__ cls,
    const float* __restrict__ abs_pos, const float* __restrict__ file_tab,
    const float* __restrict__ rank_tab, const float* __restrict__ diag_tab,
    const float* __restrict__ anti_tab, float* __restrict__ t, long xoff)
{
  long tok = blockIdx.x;
  int lane = threadIdx.x;
  long b = tok/SEQ;
  int s = (int)(tok - b*SEQ);
  float* out = t + tok*DMODEL;
  if(s==0){
    #pragma unroll
    for(int j=0;j<8;j++){ int d=lane*8+j; out[d]=cls[d]; }
    return;
  }
  int p = s-1;
  int f = p&7, r = p>>3;
  int dg = r+f, ad = r-f+7;
  float xv[16];
  #pragma unroll
  for(int k=0;k<16;k++) xv[k]=x[xoff + (b*64+p)*16+k];
  #pragma unroll
  for(int j=0;j<8;j++){
    int d = lane*8+j;
    float acc = emb_b[d] + abs_pos[p*512+d] + file_tab[f*512+d]
              + rank_tab[r*512+d] + diag_tab[dg*512+d] + anti_tab[ad*512+d];
    #pragma unroll
    for(int k=0;k<16;k++) acc += xv[k]*emb_W[k*512+d];
    out[d]=acc;
  }
}

// ---------------- LayerNorm: t(fp32) -> h(bf16) ----------------
__global__ __launch_bounds__(64) void ln_kernel(const float* __restrict__ t, ushort* __restrict__ h,
                                                const float* __restrict__ g, const float* __restrict__ b,
                                                long goff)
{
  long tok = blockIdx.x;
  int lane = threadIdx.x;
  const float* row = t + tok*DMODEL;
  float4 v0 = *reinterpret_cast<const float4*>(row + lane*8);
  float4 v1 = *reinterpret_cast<const float4*>(row + lane*8 + 4);
  float x[8] = {v0.x,v0.y,v0.z,v0.w,v1.x,v1.y,v1.z,v1.w};
  float s=0.f, ss=0.f;
  #pragma unroll
  for(int j=0;j<8;j++){ s+=x[j]; ss+=x[j]*x[j]; }
  #pragma unroll
  for(int off=32;off>=1;off>>=1){ s+=__shfl_down(s,off); ss+=__shfl_down(ss,off); }
  s=__shfl(s,0); ss=__shfl(ss,0);
  float mean = s*(1.0f/512.0f);
  float var  = ss*(1.0f/512.0f) - mean*mean;
  float rs = rsqrtf(fmaxf(var,0.0f) + 1e-5f);
  #pragma unroll
  for(int j=0;j<8;j++){
    int d=lane*8+j;
    h[tok*DMODEL+d] = f2bf((x[j]-mean)*rs*g[goff+d] + b[goff+d]);
  }
}

// ---------------- GEMM: C[M][N] = A[M][lda] @ BT[N][K]^T + bias(bf16) ----------------
// EPI 0: Cb = acc+bias (bf16)
// EPI 1: Cf += acc+bias (fp32 residual)
// EPI 2: GEGLU — BT columns interleaved (x1,x2); even lanes write gelu(x1)*x2 at col n>>1
template<int EPI>
__global__ __launch_bounds__(256,2) void gemm_bt(
    const ushort* __restrict__ A, long lda,
    const ushort* __restrict__ BT,
    const ushort* __restrict__ bias,
    ushort* __restrict__ Cb, float* __restrict__ Cf,
    long ldc, int K)
{
  __shared__ __align__(16) ushort As[128*32];
  __shared__ __align__(16) ushort Bs[128*32];
  const int tid = threadIdx.x;
  const int w = tid>>6, lane = tid&63, q = lane>>4, lr = lane&15;
  const int wm = (w>>1)*64, wn = (w&1)*64;
  const long mBase = (long)blockIdx.y*128, nBase = (long)blockIdx.x*128;

  f32x4 acc[4][4];
  #pragma unroll
  for(int i=0;i<4;i++)
    #pragma unroll
    for(int j=0;j<4;j++) acc[i][j]=(f32x4)(0.0f);

  const int idx0=tid, idx1=tid+256;
  const int ar0=idx0>>2, ac0=(idx0&3)*8;
  const int ar1=idx1>>2, ac1=(idx1&3)*8;

  for(int k0=0;k0<K;k0+=32){
    uint4 a0 = *reinterpret_cast<const uint4*>(A  + (mBase+ar0)*lda     + k0 + ac0);
    uint4 a1 = *reinterpret_cast<const uint4*>(A  + (mBase+ar1)*lda     + k0 + ac1);
    uint4 b0 = *reinterpret_cast<const uint4*>(BT + (nBase+ar0)*(long)K + k0 + ac0);
    uint4 b1 = *reinterpret_cast<const uint4*>(BT + (nBase+ar1)*(long)K + k0 + ac1);
    __syncthreads();
    reinterpret_cast<uint4*>(As)[idx0]=a0;
    reinterpret_cast<uint4*>(As)[idx1]=a1;
    reinterpret_cast<uint4*>(Bs)[idx0]=b0;
    reinterpret_cast<uint4*>(Bs)[idx1]=b1;
    __syncthreads();
    short8 af[4], bfr[4];
    #pragma unroll
    for(int mt=0;mt<4;mt++) af[mt]=*reinterpret_cast<const short8*>(As + (wm+mt*16+lr)*32 + q*8);
    #pragma unroll
    for(int nt=0;nt<4;nt++) bfr[nt]=*reinterpret_cast<const short8*>(Bs + (wn+nt*16+lr)*32 + q*8);
    #pragma unroll
    for(int mt=0;mt<4;mt++)
      #pragma unroll
      for(int nt=0;nt<4;nt++)
        acc[mt][nt]=__builtin_amdgcn_mfma_f32_16x16x32_bf16(af[mt],bfr[nt],acc[mt][nt],0,0,0);
  }

  #pragma unroll
  for(int nt=0;nt<4;nt++){
    long n = nBase+wn+nt*16+lr;
    float bv = bf2f(bias[n]);
    #pragma unroll
    for(int mt=0;mt<4;mt++){
      #pragma unroll
      for(int r=0;r<4;r++){
        long m = mBase+wm+mt*16+q*4+r;
        float v = acc[mt][nt][r]+bv;
        if constexpr (EPI==0){
          Cb[m*ldc+n]=f2bf(v);
        } else if constexpr (EPI==1){
          Cf[m*ldc+n]+=v;
        } else {
          float partner = __shfl_xor(v,1);
          if(!(lane&1)) Cb[m*ldc + (n>>1)] = f2bf(gelu_exact(v)*partner);
        }
      }
    }
  }
}

// ---------------- fused attention per (b,h): scores+bias+softmax+AV ----------------
// Q/V in LDS as f32 [s][d]; K transposed [d][s] stride 68 (conflict-free float4 reads).
__global__ __launch_bounds__(256) void attn_kernel(const ushort* __restrict__ qkv,
                                                   const float* __restrict__ rel_bias,
                                                   ushort* __restrict__ ctx, int layer)
{
  int bh = blockIdx.x;
  long b = bh>>3;
  int h = bh&7;
  __shared__ __align__(16) float Qs[SEQ*64];
  __shared__ __align__(16) float KsT[64*68];
  __shared__ __align__(16) float Vs[SEQ*64];
  __shared__ __align__(16) float Sc[SEQ*SEQ];
  __shared__ float relb[225];
  const long tokBase = b*SEQ;
  const int tid = threadIdx.x;
  for(int idx=tid; idx<SEQ*64; idx+=256){
    int s=idx>>6, d=idx&63;
    long base=(tokBase+s)*1536 + h*64 + d;
    Qs[idx]     = bf2f(qkv[base]);
    KsT[d*68+s] = bf2f(qkv[base+512]);
    Vs[idx]     = bf2f(qkv[base+1024]);
  }
  if(tid<225) relb[tid] = rel_bias[((long)layer*225 + tid)*8 + h];
  __syncthreads();

  // scores: 4-wide over ki
  const f32x4* K4 = reinterpret_cast<const f32x4*>(KsT);
  for(int i2=tid; i2<SEQ*17; i2+=256){
    int qi = i2/17, kt = i2 - qi*17;
    f32x4 a = (f32x4)(0.0f);
    #pragma unroll 8
    for(int d=0;d<64;d++){
      a += Qs[qi*64+d] * K4[d*17+kt];
    }
    int kiBase = kt*4;
    #pragma unroll
    for(int j=0;j<4;j++){
      int ki = kiBase+j;
      if(ki<SEQ){
        float s = a[j]*0.125f;
        if(qi>0 && ki>0){
          int pq=qi-1, pk=ki-1;
          int ridx=(pq>>3)-(pk>>3)+7, fidx=(pq&7)-(pk&7)+7;
          s += relb[ridx*15+fidx];
        }
        Sc[qi*SEQ+ki]=s;
      }
    }
  }
  __syncthreads();
  for(int qi=tid; qi<SEQ; qi+=256){
    float mx=-1e30f;
    for(int k=0;k<SEQ;k++) mx=fmaxf(mx,Sc[qi*SEQ+k]);
    float sum=0.f;
    for(int k=0;k<SEQ;k++){ float e=expf(Sc[qi*SEQ+k]-mx); Sc[qi*SEQ+k]=e; sum+=e; }
    float inv=1.0f/sum;
    for(int k=0;k<SEQ;k++) Sc[qi*SEQ+k]*=inv;
  }
  __syncthreads();
  // AV: 4-wide over d
  const f32x4* V4 = reinterpret_cast<const f32x4*>(Vs);
  for(int i2=tid; i2<SEQ*16; i2+=256){
    int qi = i2>>4, d4 = i2&15;
    f32x4 a = (f32x4)(0.0f);
    for(int k=0;k<SEQ;k++){
      a += Sc[qi*SEQ+k] * V4[k*16+d4];
    }
    long obase = (tokBase+qi)*512 + h*64 + d4*4;
    #pragma unroll
    for(int j=0;j<4;j++) ctx[obase+j] = f2bf(a[j]);
  }
}

// ---------------- policy head: out[(b0+bl)*4608 + p*72+j] (float) ----------------
__global__ __launch_bounds__(128) void policy_kernel(const ushort* __restrict__ h,
                                                     const float* __restrict__ pol_W,
                                                     const float* __restrict__ pol_b,
                                                     float* __restrict__ out, long b0)
{
  int bp = blockIdx.x;           // bl*64 + p
  long bl = bp>>6;
  int p = bp&63;
  const ushort* hrow = h + (bl*SEQ + 1 + p)*DMODEL;
  __shared__ float hl[DMODEL];
  for(int d=threadIdx.x; d<DMODEL; d+=128) hl[d]=bf2f(hrow[d]);
  __syncthreads();
  int j = threadIdx.x;
  if(j<72){
    float acc = pol_b[j];
    for(int k=0;k<DMODEL;k++) acc += hl[k]*pol_W[k*72+j];
    out[(b0+bl)*4608 + (long)p*72 + j] = acc;
  }
}

// ---------------- value head MLP on CLS token (float out) ----------------
__global__ __launch_bounds__(256) void value_kernel(const ushort* __restrict__ h,
                                                    const float* __restrict__ v1_W, const float* __restrict__ v1_b,
                                                    const float* __restrict__ v2_W, const float* __restrict__ v2_b,
                                                    const float* __restrict__ v3_W, const float* __restrict__ v3_b,
                                                    float* __restrict__ out, long b0)
{
  long bl = blockIdx.x;
  int tid = threadIdx.x;
  __shared__ float vh[512], a1[256], a2[128];
  const ushort* hrow = h + bl*SEQ*DMODEL;   // CLS token
  for(int d=tid; d<512; d+=256) vh[d]=bf2f(hrow[d]);
  __syncthreads();
  {
    float acc = v1_b[tid];
    for(int k=0;k<512;k++) acc += vh[k]*v1_W[k*256+tid];
    a1[tid]=gelu_exact(acc);
  }
  __syncthreads();
  if(tid<128){
    float acc = v2_b[tid];
    for(int k=0;k<256;k++) acc += a1[k]*v2_W[k*128+tid];
    a2[tid]=gelu_exact(acc);
  }
  __syncthreads();
  if(tid==0){
    float acc = v3_b[0];
    for(int k=0;k<128;k++) acc += a2[k]*v3_W[k];
    out[(long)BATCH*4608 + b0 + bl] = tanhf(acc);
  }
}

extern "C" void kernel_launch(void* const* d_in, const int* in_sizes, int n_in,
                              void* d_out, int out_size, void* d_ws, size_t ws_size,
                              hipStream_t stream)
{
  const float* x        = (const float*)d_in[0];
  const float* emb_W    = (const float*)d_in[1];
  const float* emb_b    = (const float*)d_in[2];
  const float* cls      = (const float*)d_in[3];
  const float* abs_pos  = (const float*)d_in[4];
  const float* file_tab = (const float*)d_in[5];
  const float* rank_tab = (const float*)d_in[6];
  const float* diag_tab = (const float*)d_in[7];
  const float* anti_tab = (const float*)d_in[8];
  const float* rel_bias = (const float*)d_in[9];
  const float* Wq  = (const float*)d_in[10];
  const float* bq  = (const float*)d_in[11];
  const float* Wk  = (const float*)d_in[12];
  const float* bk  = (const float*)d_in[13];
  const float* Wv  = (const float*)d_in[14];
  const float* bv  = (const float*)d_in[15];
  const float* Wo  = (const float*)d_in[16];
  const float* bo  = (const float*)d_in[17];
  const float* ln1_g = (const float*)d_in[18];
  const float* ln1_b = (const float*)d_in[19];
  const float* ln2_g = (const float*)d_in[20];
  const float* ln2_b = (const float*)d_in[21];
  const float* W1  = (const float*)d_in[22];
  const float* b1  = (const float*)d_in[23];
  const float* W2  = (const float*)d_in[24];
  const float* b2  = (const float*)d_in[25];
  const float* fln_g = (const float*)d_in[26];
  const float* fln_b = (const float*)d_in[27];
  const float* pol_W = (const float*)d_in[28];
  const float* pol_b = (const float*)d_in[29];
  const float* v1_W  = (const float*)d_in[30];
  const float* v1_b  = (const float*)d_in[31];
  const float* v2_W  = (const float*)d_in[32];
  const float* v2_b  = (const float*)d_in[33];
  const float* v3_W  = (const float*)d_in[34];
  const float* v3_b  = (const float*)d_in[35];
  float* out = (float*)d_out;

  char* ws = (char*)d_ws;
  float*  t    = (float*)ws;  ws += (size_t)MCH*DMODEL*4;   // 34.1 MB
  ushort* h    = (ushort*)ws; ws += (size_t)MCH*DMODEL*2;   // 17.0 MB (also ctx)
  ushort* buf1 = (ushort*)ws; ws += (size_t)MCH*1536*2;     // 51.1 MB (qkv / geglu out)
  ushort* wT   = (ushort*)ws; ws += (size_t)WT_TOTAL*2;     // 68.3 MB
  (void)ws_size; (void)in_sizes; (void)n_in; (void)out_size;
  // total 170.5 MB

  // --- one-time weight prep ---
  prep_qkv<<<(7864320+255)/256,256,0,stream>>>(Wq,Wk,Wv,wT);
  prep_wo <<<(2621440+255)/256,256,0,stream>>>(Wo,wT);
  prep_w1 <<<(15728640+255)/256,256,0,stream>>>(W1,wT);
  prep_w2 <<<(7864320+255)/256,256,0,stream>>>(W2,wT);
  prep_bias<<<(56320+255)/256,256,0,stream>>>(bq,bk,bv,bo,b1,b2,wT);

  // --- per-chunk full network ---
  for(int c=0;c<NCHUNK;c++){
    long b0 = (long)c*BCH;
    embed_kernel<<<MCH,64,0,stream>>>(x, emb_W, emb_b, cls, abs_pos,
                                      file_tab, rank_tab, diag_tab, anti_tab, t, b0*64*16);
    for(int l=0;l<NLAYER;l++){
      ln_kernel<<<MCH,64,0,stream>>>(t, h, ln1_g, ln1_b, l*512);
      gemm_bt<0><<<dim3(12,130),256,0,stream>>>(h, 512, wT+WT_QKV+(long)l*786432,
                                                wT+WT_BQKV+l*1536, buf1, nullptr, 1536, 512);
      attn_kernel<<<BCH*NHEAD,256,0,stream>>>(buf1, rel_bias, h, l);   // ctx -> h
      gemm_bt<1><<<dim3(4,130),256,0,stream>>>(h, 512, wT+WT_WO+(long)l*262144,
                                               wT+WT_BO+l*512, nullptr, t, 512, 512);
      ln_kernel<<<MCH,64,0,stream>>>(t, h, ln2_g, ln2_b, l*512);
      gemm_bt<2><<<dim3(24,130),256,0,stream>>>(h, 512, wT+WT_W1+(long)l*1572864,
                                                wT+WT_B1+l*3072, buf1, nullptr, 1536, 512);
      gemm_bt<1><<<dim3(4,130),256,0,stream>>>(buf1, 1536, wT+WT_W2+(long)l*786432,
                                               wT+WT_B2+l*512, nullptr, t, 512, 1536);
    }
    ln_kernel<<<MCH,64,0,stream>>>(t, h, fln_g, fln_b, 0);
    policy_kernel<<<BCH*64,128,0,stream>>>(h, pol_W, pol_b, out, b0);
    value_kernel<<<BCH,256,0,stream>>>(h, v1_W, v1_b, v2_W, v2_b, v3_W, v3_b, out, b0);
  }
}

// Round 7
// 17565.665 us; speedup vs baseline: 1.5762x; 1.0167x over previous
//
#include <hip/hip_runtime.h>
#include <hip/hip_bf16.h>
#include <math.h>

// TitanMini forward: B=1024, S=65 (CLS+64), D=512, H=8, DK=64, DFF=1536 (GEGLU), L=10
// Inputs/outputs FLOAT32 (verified r5). Internal: bf16 MFMA GEMMs + fp32 residual.
// r7: GEMM staging via __builtin_amdgcn_global_load_lds width=16 (m97 2-barrier K-loop).

typedef short short8 __attribute__((ext_vector_type(8)));
typedef float f32x4 __attribute__((ext_vector_type(4)));

#define NLAYER 10
#define DMODEL 512
#define NHEAD 8
#define BATCH 1024
#define SEQ 65
#define NCHUNK 4
#define BCH (BATCH/NCHUNK)      // 256
#define MCH (BCH*SEQ)           // 16640 = 130*128

// wT element offsets (ushort)
#define WT_QKV   0L            // 10*1536*512
#define WT_WO    7864320L      // 10*512*512
#define WT_W1    10485760L     // 10*3072*512 (columns interleaved x1/x2)
#define WT_W2    26214400L     // 10*512*1536
#define WT_BQKV  34078720L     // 10*1536
#define WT_BO    34094080L     // 10*512
#define WT_B1    34099200L     // 10*3072 (interleaved)
#define WT_B2    34129920L     // 10*512
#define WT_TOTAL 34135040L

__device__ __forceinline__ float bf2f(ushort u){ return __uint_as_float(((unsigned)u)<<16); }
__device__ __forceinline__ ushort f2bf(float f){
  unsigned u = __float_as_uint(f);
  unsigned r = (u + 0x7fffu + ((u>>16)&1u)) >> 16;
  return (ushort)r;
}
__device__ __forceinline__ float gelu_exact(float x){
  return 0.5f*x*(1.0f+erff(x*0.70710678118654752440f));
}
// async global->LDS, 16B per lane; LDS dest must be wave-uniform base + lane*16
__device__ __forceinline__ void gl16(ushort* lds, const ushort* g){
  __builtin_amdgcn_global_load_lds(
      (const unsigned int __attribute__((address_space(1)))*)g,
      (unsigned int __attribute__((address_space(3)))*)lds,
      16, 0, 0);
}

// ---------------- one-time weight prep: f32 -> transposed bf16 ----------------
__global__ void prep_qkv(const float* __restrict__ Wq, const float* __restrict__ Wk,
                         const float* __restrict__ Wv, ushort* __restrict__ wT)
{
  long idx = (long)blockIdx.x*256 + threadIdx.x;
  if(idx >= 7864320L) return;
  int l = (int)(idx/786432L);
  long r = idx - (long)l*786432L;
  int n = (int)(r>>9), k = (int)(r&511);
  float v;
  if(n<512)       v = Wq[(long)l*262144 + (long)k*512 + n];
  else if(n<1024) v = Wk[(long)l*262144 + (long)k*512 + (n-512)];
  else            v = Wv[(long)l*262144 + (long)k*512 + (n-1024)];
  wT[WT_QKV + idx] = f2bf(v);
}
__global__ void prep_wo(const float* __restrict__ Wo, ushort* __restrict__ wT)
{
  long idx = (long)blockIdx.x*256 + threadIdx.x;
  if(idx >= 2621440L) return;
  int l = (int)(idx/262144L);
  long r = idx - (long)l*262144L;
  int n = (int)(r>>9), k = (int)(r&511);
  wT[WT_WO + idx] = f2bf(Wo[(long)l*262144 + (long)k*512 + n]);
}
__global__ void prep_w1(const float* __restrict__ W1, ushort* __restrict__ wT)
{
  long idx = (long)blockIdx.x*256 + threadIdx.x;
  if(idx >= 15728640L) return;
  int l = (int)(idx/1572864L);
  long r = idx - (long)l*1572864L;
  int n = (int)(r>>9), k = (int)(r&511);
  int j = n>>1;
  int src = (n&1) ? 1536+j : j;       // even n -> x1 col j, odd n -> x2 col j
  wT[WT_W1 + idx] = f2bf(W1[(long)l*1572864 + (long)k*3072 + src]);
}
__global__ void prep_w2(const float* __restrict__ W2, ushort* __restrict__ wT)
{
  long idx = (long)blockIdx.x*256 + threadIdx.x;
  if(idx >= 7864320L) return;
  int l = (int)(idx/786432L);
  long r = idx - (long)l*786432L;
  int n = (int)(r/1536), k = (int)(r - (long)n*1536);
  wT[WT_W2 + idx] = f2bf(W2[(long)l*786432 + (long)k*512 + n]);
}
__global__ void prep_bias(const float* __restrict__ bq, const float* __restrict__ bk,
                          const float* __restrict__ bv, const float* __restrict__ bo,
                          const float* __restrict__ b1, const float* __restrict__ b2,
                          ushort* __restrict__ wT)
{
  int idx = blockIdx.x*256 + threadIdx.x;
  if(idx >= 56320) return;
  long o = WT_BQKV + idx;
  float v;
  if(o < WT_BO){
    int i = idx;                 // bqkv: l*1536 + n
    int l = i/1536, n = i - l*1536;
    if(n<512) v=bq[l*512+n]; else if(n<1024) v=bk[l*512+n-512]; else v=bv[l*512+n-1024];
  } else if(o < WT_B1){
    int i = (int)(o - WT_BO);
    v = bo[i];
  } else if(o < WT_B2){
    int i = (int)(o - WT_B1);    // b1 interleaved: l*3072 + n
    int l = i/3072, n = i - l*3072;
    int j=n>>1; int src=(n&1)?1536+j:j;
    v = b1[l*3072+src];
  } else {
    int i = (int)(o - WT_B2);
    v = b2[i];
  }
  wT[o] = f2bf(v);
}

// ---------------- embedding + positional tables -> t (fp32), chunk-local ----------------
__global__ __launch_bounds__(64) void embed_kernel(
    const float* __restrict__ x, const float* __restrict__ emb_W,
    const float* __restrict__ emb_b, const float* __restrict__ cls,
    const float* __restrict__ abs_pos, const float* __restrict__ file_tab,
    const float* __restrict__ rank_tab, const float* __restrict__ diag_tab,
    const float* __restrict__ anti_tab, float* __restrict__ t, long xoff)
{
  long tok = blockIdx.x;
  int lane = threadIdx.x;
  long b = tok/SEQ;
  int s = (int)(tok - b*SEQ);
  float* out = t + tok*DMODEL;
  if(s==0){
    #pragma unroll
    for(int j=0;j<8;j++){ int d=lane*8+j; out[d]=cls[d]; }
    return;
  }
  int p = s-1;
  int f = p&7, r = p>>3;
  int dg = r+f, ad = r-f+7;
  float xv[16];
  #pragma unroll
  for(int k=0;k<16;k++) xv[k]=x[xoff + (b*64+p)*16+k];
  #pragma unroll
  for(int j=0;j<8;j++){
    int d = lane*8+j;
    float acc = emb_b[d] + abs_pos[p*512+d] + file_tab[f*512+d]
              + rank_tab[r*512+d] + diag_tab[dg*512+d] + anti_tab[ad*512+d];
    #pragma unroll
    for(int k=0;k<16;k++) acc += xv[k]*emb_W[k*512+d];
    out[d]=acc;
  }
}

// ---------------- LayerNorm: t(fp32) -> h(bf16) ----------------
__global__ __launch_bounds__(64) void ln_kernel(const float* __restrict__ t, ushort* __restrict__ h,
                                                const float* __restrict__ g, const float* __restrict__ b,
                                                long goff)
{
  long tok = blockIdx.x;
  int lane = threadIdx.x;
  const float* row = t + tok*DMODEL;
  float4 v0 = *reinterpret_cast<const float4*>(row + lane*8);
  float4 v1 = *reinterpret_cast<const float4*>(row + lane*8 + 4);
  float x[8] = {v0.x,v0.y,v0.z,v0.w,v1.x,v1.y,v1.z,v1.w};
  float s=0.f, ss=0.f;
  #pragma unroll
  for(int j=0;j<8;j++){ s+=x[j]; ss+=x[j]*x[j]; }
  #pragma unroll
  for(int off=32;off>=1;off>>=1){ s+=__shfl_down(s,off); ss+=__shfl_down(ss,off); }
  s=__shfl(s,0); ss=__shfl(ss,0);
  float mean = s*(1.0f/512.0f);
  float var  = ss*(1.0f/512.0f) - mean*mean;
  float rs = rsqrtf(fmaxf(var,0.0f) + 1e-5f);
  #pragma unroll
  for(int j=0;j<8;j++){
    int d=lane*8+j;
    h[tok*DMODEL+d] = f2bf((x[j]-mean)*rs*g[goff+d] + b[goff+d]);
  }
}

// ---------------- GEMM: C[M][N] = A[M][lda] @ BT[N][K]^T + bias(bf16) ----------------
// Staging: global_load_lds width=16 (async, m97 2-barrier K-loop).
// EPI 0: Cb = acc+bias (bf16)
// EPI 1: Cf += acc+bias (fp32 residual)
// EPI 2: GEGLU — BT columns interleaved (x1,x2); even lanes write gelu(x1)*x2 at col n>>1
template<int EPI>
__global__ __launch_bounds__(256,2) void gemm_bt(
    const ushort* __restrict__ A, long lda,
    const ushort* __restrict__ BT,
    const ushort* __restrict__ bias,
    ushort* __restrict__ Cb, float* __restrict__ Cf,
    long ldc, int K)
{
  __shared__ __align__(16) ushort As[128*32];
  __shared__ __align__(16) ushort Bs[128*32];
  const int tid = threadIdx.x;
  const int w = tid>>6, lane = tid&63, q = lane>>4, lr = lane&15;
  const int wm = (w>>1)*64, wn = (w&1)*64;
  const long mBase = (long)blockIdx.y*128, nBase = (long)blockIdx.x*128;

  f32x4 acc[4][4];
  #pragma unroll
  for(int i=0;i<4;i++)
    #pragma unroll
    for(int j=0;j<4;j++) acc[i][j]=(f32x4)(0.0f);

  const int idx0=tid, idx1=tid+256;
  const int ar0=idx0>>2, ac0=(idx0&3)*8;
  const int ar1=idx1>>2, ac1=(idx1&3)*8;

  const ushort* gA0 = A  + (mBase+ar0)*lda     + ac0;
  const ushort* gA1 = A  + (mBase+ar1)*lda     + ac1;
  const ushort* gB0 = BT + (nBase+ar0)*(long)K + ac0;
  const ushort* gB1 = BT + (nBase+ar1)*(long)K + ac1;
  ushort* lA0 = As + idx0*8;   // = LDS byte offset idx0*16: wave-uniform base + lane*16
  ushort* lA1 = As + idx1*8;
  ushort* lB0 = Bs + idx0*8;
  ushort* lB1 = Bs + idx1*8;

  for(int k0=0;k0<K;k0+=32){
    __syncthreads();                 // prev iter's ds_reads done before overwrite
    gl16(lA0, gA0 + k0);
    gl16(lA1, gA1 + k0);
    gl16(lB0, gB0 + k0);
    gl16(lB1, gB1 + k0);
    __syncthreads();                 // compiler emits vmcnt(0) drain -> LDS valid
    short8 af[4], bfr[4];
    #pragma unroll
    for(int mt=0;mt<4;mt++) af[mt]=*reinterpret_cast<const short8*>(As + (wm+mt*16+lr)*32 + q*8);
    #pragma unroll
    for(int nt=0;nt<4;nt++) bfr[nt]=*reinterpret_cast<const short8*>(Bs + (wn+nt*16+lr)*32 + q*8);
    #pragma unroll
    for(int mt=0;mt<4;mt++)
      #pragma unroll
      for(int nt=0;nt<4;nt++)
        acc[mt][nt]=__builtin_amdgcn_mfma_f32_16x16x32_bf16(af[mt],bfr[nt],acc[mt][nt],0,0,0);
  }

  #pragma unroll
  for(int nt=0;nt<4;nt++){
    long n = nBase+wn+nt*16+lr;
    float bv = bf2f(bias[n]);
    #pragma unroll
    for(int mt=0;mt<4;mt++){
      #pragma unroll
      for(int r=0;r<4;r++){
        long m = mBase+wm+mt*16+q*4+r;
        float v = acc[mt][nt][r]+bv;
        if constexpr (EPI==0){
          Cb[m*ldc+n]=f2bf(v);
        } else if constexpr (EPI==1){
          Cf[m*ldc+n]+=v;
        } else {
          float partner = __shfl_xor(v,1);
          if(!(lane&1)) Cb[m*ldc + (n>>1)] = f2bf(gelu_exact(v)*partner);
        }
      }
    }
  }
}

// ---------------- fused attention per (b,h): scores+bias+softmax+AV ----------------
// Q/V in LDS as f32 [s][d]; K transposed [d][s] stride 68 (conflict-free float4 reads).
__global__ __launch_bounds__(256) void attn_kernel(const ushort* __restrict__ qkv,
                                                   const float* __restrict__ rel_bias,
                                                   ushort* __restrict__ ctx, int layer)
{
  int bh = blockIdx.x;
  long b = bh>>3;
  int h = bh&7;
  __shared__ __align__(16) float Qs[SEQ*64];
  __shared__ __align__(16) float KsT[64*68];
  __shared__ __align__(16) float Vs[SEQ*64];
  __shared__ __align__(16) float Sc[SEQ*SEQ];
  __shared__ float relb[225];
  const long tokBase = b*SEQ;
  const int tid = threadIdx.x;
  for(int idx=tid; idx<SEQ*64; idx+=256){
    int s=idx>>6, d=idx&63;
    long base=(tokBase+s)*1536 + h*64 + d;
    Qs[idx]     = bf2f(qkv[base]);
    KsT[d*68+s] = bf2f(qkv[base+512]);
    Vs[idx]     = bf2f(qkv[base+1024]);
  }
  if(tid<225) relb[tid] = rel_bias[((long)layer*225 + tid)*8 + h];
  __syncthreads();

  // scores: 4-wide over ki
  const f32x4* K4 = reinterpret_cast<const f32x4*>(KsT);
  for(int i2=tid; i2<SEQ*17; i2+=256){
    int qi = i2/17, kt = i2 - qi*17;
    f32x4 a = (f32x4)(0.0f);
    #pragma unroll 8
    for(int d=0;d<64;d++){
      a += Qs[qi*64+d] * K4[d*17+kt];
    }
    int kiBase = kt*4;
    #pragma unroll
    for(int j=0;j<4;j++){
      int ki = kiBase+j;
      if(ki<SEQ){
        float s = a[j]*0.125f;
        if(qi>0 && ki>0){
          int pq=qi-1, pk=ki-1;
          int ridx=(pq>>3)-(pk>>3)+7, fidx=(pq&7)-(pk&7)+7;
          s += relb[ridx*15+fidx];
        }
        Sc[qi*SEQ+ki]=s;
      }
    }
  }
  __syncthreads();
  for(int qi=tid; qi<SEQ; qi+=256){
    float mx=-1e30f;
    for(int k=0;k<SEQ;k++) mx=fmaxf(mx,Sc[qi*SEQ+k]);
    float sum=0.f;
    for(int k=0;k<SEQ;k++){ float e=expf(Sc[qi*SEQ+k]-mx); Sc[qi*SEQ+k]=e; sum+=e; }
    float inv=1.0f/sum;
    for(int k=0;k<SEQ;k++) Sc[qi*SEQ+k]*=inv;
  }
  __syncthreads();
  // AV: 4-wide over d
  const f32x4* V4 = reinterpret_cast<const f32x4*>(Vs);
  for(int i2=tid; i2<SEQ*16; i2+=256){
    int qi = i2>>4, d4 = i2&15;
    f32x4 a = (f32x4)(0.0f);
    for(int k=0;k<SEQ;k++){
      a += Sc[qi*SEQ+k] * V4[k*16+d4];
    }
    long obase = (tokBase+qi)*512 + h*64 + d4*4;
    #pragma unroll
    for(int j=0;j<4;j++) ctx[obase+j] = f2bf(a[j]);
  }
}

// ---------------- policy head: out[(b0+bl)*4608 + p*72+j] (float) ----------------
__global__ __launch_bounds__(128) void policy_kernel(const ushort* __restrict__ h,
                                                     const float* __restrict__ pol_W,
                                                     const float* __restrict__ pol_b,
                                                     float* __restrict__ out, long b0)
{
  int bp = blockIdx.x;           // bl*64 + p
  long bl = bp>>6;
  int p = bp&63;
  const ushort* hrow = h + (bl*SEQ + 1 + p)*DMODEL;
  __shared__ float hl[DMODEL];
  for(int d=threadIdx.x; d<DMODEL; d+=128) hl[d]=bf2f(hrow[d]);
  __syncthreads();
  int j = threadIdx.x;
  if(j<72){
    float acc = pol_b[j];
    for(int k=0;k<DMODEL;k++) acc += hl[k]*pol_W[k*72+j];
    out[(b0+bl)*4608 + (long)p*72 + j] = acc;
  }
}

// ---------------- value head MLP on CLS token (float out) ----------------
__global__ __launch_bounds__(256) void value_kernel(const ushort* __restrict__ h,
                                                    const float* __restrict__ v1_W, const float* __restrict__ v1_b,
                                                    const float* __restrict__ v2_W, const float* __restrict__ v2_b,
                                                    const float* __restrict__ v3_W, const float* __restrict__ v3_b,
                                                    float* __restrict__ out, long b0)
{
  long bl = blockIdx.x;
  int tid = threadIdx.x;
  __shared__ float vh[512], a1[256], a2[128];
  const ushort* hrow = h + bl*SEQ*DMODEL;   // CLS token
  for(int d=tid; d<512; d+=256) vh[d]=bf2f(hrow[d]);
  __syncthreads();
  {
    float acc = v1_b[tid];
    for(int k=0;k<512;k++) acc += vh[k]*v1_W[k*256+tid];
    a1[tid]=gelu_exact(acc);
  }
  __syncthreads();
  if(tid<128){
    float acc = v2_b[tid];
    for(int k=0;k<256;k++) acc += a1[k]*v2_W[k*128+tid];
    a2[tid]=gelu_exact(acc);
  }
  __syncthreads();
  if(tid==0){
    float acc = v3_b[0];
    for(int k=0;k<128;k++) acc += a2[k]*v3_W[k];
    out[(long)BATCH*4608 + b0 + bl] = tanhf(acc);
  }
}

extern "C" void kernel_launch(void* const* d_in, const int* in_sizes, int n_in,
                              void* d_out, int out_size, void* d_ws, size_t ws_size,
                              hipStream_t stream)
{
  const float* x        = (const float*)d_in[0];
  const float* emb_W    = (const float*)d_in[1];
  const float* emb_b    = (const float*)d_in[2];
  const float* cls      = (const float*)d_in[3];
  const float* abs_pos  = (const float*)d_in[4];
  const float* file_tab = (const float*)d_in[5];
  const float* rank_tab = (const float*)d_in[6];
  const float* diag_tab = (const float*)d_in[7];
  const float* anti_tab = (const float*)d_in[8];
  const float* rel_bias = (const float*)d_in[9];
  const float* Wq  = (const float*)d_in[10];
  const float* bq  = (const float*)d_in[11];
  const float* Wk  = (const float*)d_in[12];
  const float* bk  = (const float*)d_in[13];
  const float* Wv  = (const float*)d_in[14];
  const float* bv  = (const float*)d_in[15];
  const float* Wo  = (const float*)d_in[16];
  const float* bo  = (const float*)d_in[17];
  const float* ln1_g = (const float*)d_in[18];
  const float* ln1_b = (const float*)d_in[19];
  const float* ln2_g = (const float*)d_in[20];
  const float* ln2_b = (const float*)d_in[21];
  const float* W1  = (const float*)d_in[22];
  const float* b1  = (const float*)d_in[23];
  const float* W2  = (const float*)d_in[24];
  const float* b2  = (const float*)d_in[25];
  const float* fln_g = (const float*)d_in[26];
  const float* fln_b = (const float*)d_in[27];
  const float* pol_W = (const float*)d_in[28];
  const float* pol_b = (const float*)d_in[29];
  const float* v1_W  = (const float*)d_in[30];
  const float* v1_b  = (const float*)d_in[31];
  const float* v2_W  = (const float*)d_in[32];
  const float* v2_b  = (const float*)d_in[33];
  const float* v3_W  = (const float*)d_in[34];
  const float* v3_b  = (const float*)d_in[35];
  float* out = (float*)d_out;

  char* ws = (char*)d_ws;
  float*  t    = (float*)ws;  ws += (size_t)MCH*DMODEL*4;   // 34.1 MB
  ushort* h    = (ushort*)ws; ws += (size_t)MCH*DMODEL*2;   // 17.0 MB (also ctx)
  ushort* buf1 = (ushort*)ws; ws += (size_t)MCH*1536*2;     // 51.1 MB (qkv / geglu out)
  ushort* wT   = (ushort*)ws; ws += (size_t)WT_TOTAL*2;     // 68.3 MB
  (void)ws_size; (void)in_sizes; (void)n_in; (void)out_size;
  // total 170.5 MB

  // --- one-time weight prep ---
  prep_qkv<<<(7864320+255)/256,256,0,stream>>>(Wq,Wk,Wv,wT);
  prep_wo <<<(2621440+255)/256,256,0,stream>>>(Wo,wT);
  prep_w1 <<<(15728640+255)/256,256,0,stream>>>(W1,wT);
  prep_w2 <<<(7864320+255)/256,256,0,stream>>>(W2,wT);
  prep_bias<<<(56320+255)/256,256,0,stream>>>(bq,bk,bv,bo,b1,b2,wT);

  // --- per-chunk full network ---
  for(int c=0;c<NCHUNK;c++){
    long b0 = (long)c*BCH;
    embed_kernel<<<MCH,64,0,stream>>>(x, emb_W, emb_b, cls, abs_pos,
                                      file_tab, rank_tab, diag_tab, anti_tab, t, b0*64*16);
    for(int l=0;l<NLAYER;l++){
      ln_kernel<<<MCH,64,0,stream>>>(t, h, ln1_g, ln1_b, l*512);
      gemm_bt<0><<<dim3(12,130),256,0,stream>>>(h, 512, wT+WT_QKV+(long)l*786432,
                                                wT+WT_BQKV+l*1536, buf1, nullptr, 1536, 512);
      attn_kernel<<<BCH*NHEAD,256,0,stream>>>(buf1, rel_bias, h, l);   // ctx -> h
      gemm_bt<1><<<dim3(4,130),256,0,stream>>>(h, 512, wT+WT_WO+(long)l*262144,
                                               wT+WT_BO+l*512, nullptr, t, 512, 512);
      ln_kernel<<<MCH,64,0,stream>>>(t, h, ln2_g, ln2_b, l*512);
      gemm_bt<2><<<dim3(24,130),256,0,stream>>>(h, 512, wT+WT_W1+(long)l*1572864,
                                                wT+WT_B1+l*3072, buf1, nullptr, 1536, 512);
      gemm_bt<1><<<dim3(4,130),256,0,stream>>>(buf1, 1536, wT+WT_W2+(long)l*786432,
                                               wT+WT_B2+l*512, nullptr, t, 512, 1536);
    }
    ln_kernel<<<MCH,64,0,stream>>>(t, h, fln_g, fln_b, 0);
    policy_kernel<<<BCH*64,128,0,stream>>>(h, pol_W, pol_b, out, b0);
    value_kernel<<<BCH,256,0,stream>>>(h, v1_W, v1_b, v2_W, v2_b, v3_W, v3_b, out, b0);
  }
}